// Round 5
// baseline (283.609 us; speedup 1.0000x reference)
//
#include <hip/hip_runtime.h>
#include <hip/hip_bf16.h>
#include <cstddef>
#include <cstdint>

typedef float v4f __attribute__((ext_vector_type(4)));
typedef short v8s __attribute__((ext_vector_type(8)));
typedef _Float16 v8h __attribute__((ext_vector_type(8)));

__device__ __forceinline__ uint32_t fbits(float x){ uint32_t u; __builtin_memcpy(&u,&x,4); return u; }
__device__ __forceinline__ float ffrom(uint32_t u){ float f; __builtin_memcpy(&f,&u,4); return f; }
// round-half-up bf16
__device__ __forceinline__ short bf_rh(float x){ return (short)((fbits(x)+0x8000u)>>16); }
__device__ __forceinline__ uint32_t pack_bf_rh(float a, float b){
    uint32_t ua = fbits(a)+0x8000u, ub = fbits(b)+0x8000u;
#if __has_builtin(__builtin_amdgcn_perm)
    return __builtin_amdgcn_perm(ub, ua, 0x07060302u);
#else
    return (ua>>16) | (ub & 0xFFFF0000u);
#endif
}
// fp16 (RNE) stored in a short
__device__ __forceinline__ short f2h(float x){ _Float16 h = (_Float16)x; short s; __builtin_memcpy(&s,&h,2); return s; }
#if __has_builtin(__builtin_amdgcn_exp2f)
#define EXP2(x) __builtin_amdgcn_exp2f(x)
#else
#define EXP2(x) exp2f(x)
#endif

__device__ __forceinline__ void gld16(const void* g, void* l) {
    __builtin_amdgcn_global_load_lds(
        (const __attribute__((address_space(1))) unsigned int*)g,
        (__attribute__((address_space(3))) unsigned int*)l, 16, 0, 0);
}
#define MFMA(a,b,c)  __builtin_amdgcn_mfma_f32_16x16x32_bf16((a),(b),(c),0,0,0)
#define MFMAH(a,b,c) __builtin_amdgcn_mfma_f32_16x16x32_f16((a),(b),(c),0,0,0)

#define LOG2E 1.4426950408889634f

// ---------------------------------------------------------------------------
// K1 fused_qkv (927 blocks x 256): unchanged from round 4, plus: the first
// rpi-pack block zeroes the 64 proj-ticket counters (workspace is poisoned
// each iteration; kernel-boundary ordering makes the zeros visible to K2).
// ---------------------------------------------------------------------------
__global__ __launch_bounds__(256)
void fused_qkv(const float* __restrict__ x,   const float* __restrict__ wq,
               const float* __restrict__ wp,  const float* __restrict__ rct,
               const float* __restrict__ fc1w, const float* __restrict__ fc1b,
               const float* __restrict__ fc2w, const float* __restrict__ fc2b,
               const float* __restrict__ qkvb, const float* __restrict__ qe,
               const float* __restrict__ temp, const int* __restrict__ rpi,
               short* __restrict__ qh, short* __restrict__ kh,
               short* __restrict__ vt, float* __restrict__ tblf,
               short* __restrict__ wph, unsigned long long* __restrict__ bi,
               unsigned* __restrict__ done)
{
    __shared__ __align__(16) char smem[49152];
    int bid  = blockIdx.x;
    int tid  = threadIdx.x;
    int w    = tid >> 6;
    int lane = tid & 63;
    int t    = lane & 15;
    int quad = lane >> 4;
    int lr8  = lane >> 3, lc8 = lane & 7;

    if (bid < 63) {
        // ---- CPB MLP ----
        float* s1 = (float*)smem;      // 1024 f
        float* sb = s1 + 1024;         // 512 f
        float* s2 = sb + 512;          // 4096 f
        for (int i = tid; i < 1024; i += 256) s1[i] = fc1w[i];
        for (int i = tid; i < 512;  i += 256) sb[i] = fc1b[i];
        for (int i = tid; i < 4096; i += 256) s2[i] = fc2w[i];
        __syncthreads();
        int rl = tid >> 2, jp = tid & 3;
        bool ok = rl < 63;
        int r = bid * 63 + rl;
        float c0 = ok ? rct[2*r]   : 0.f;
        float c1 = ok ? rct[2*r+1] : 0.f;
        float a[8] = {0,0,0,0,0,0,0,0};
        int j0 = jp * 128;
        #pragma unroll 4
        for (int j = j0; j < j0 + 128; ++j) {
            float hv = fmaxf(c0*s1[2*j] + c1*s1[2*j+1] + sb[j], 0.0f);
            #pragma unroll
            for (int hh = 0; hh < 8; ++hh) a[hh] += hv * s2[hh*512 + j];
        }
        #pragma unroll
        for (int hh = 0; hh < 8; ++hh) {
            a[hh] += __shfl_xor(a[hh], 1);
            a[hh] += __shfl_xor(a[hh], 2);
        }
        if (ok && jp == 0) {
            #pragma unroll
            for (int hh = 0; hh < 8; ++hh)
                tblf[hh*3969 + r] = (a[hh] + fc2b[hh]) * LOG2E;  // pre-scaled
        }
    } else if (bid < 95) {
        // ---- proj_w fp32 -> fp16 swizzled ----
        int base8 = (bid - 63) * 256;
        int e0 = (base8 + tid) * 8;
        int m  = e0 >> 8;
        int k  = e0 & 255;
        int kt = k >> 6, c = (k >> 3) & 7;
        float4 f0 = *(const float4*)(wp + e0);
        float4 f1 = *(const float4*)(wp + e0 + 4);
        float v[8] = {f0.x,f0.y,f0.z,f0.w,f1.x,f1.y,f1.z,f1.w};
        v8s hi;
        #pragma unroll
        for (int j = 0; j < 8; ++j) hi[j] = f2h(v[j]);
        int dst = m*256 + kt*64 + ((c ^ (m & 7)) << 3);
        *(v8s*)&wph[dst] = hi;
    } else if (bid < 159) {
        // ---- rpi -> packed u16 index table, MFMA C-frag order ----
        int q16 = bid - 95;            // 0..63 (16-row group)
        if (q16 == 0 && tid < 64) done[tid] = 0;   // zero proj tickets
        int grp = tid >> 6;            // 0..3
        #pragma unroll 1
        for (int c = 0; c < 16; ++c) {
            int combo = grp*16 + c;
            int kt = combo >> 2, g = combo & 3;
            unsigned long long pk = 0;
            #pragma unroll
            for (int r = 0; r < 4; ++r) {
                int idx = rpi[(size_t)(q16*16 + quad*4 + r)*1024 + kt*64 + 4*t + g];
                pk |= (unsigned long long)(idx & 0xFFFF) << (16*r);
            }
            bi[((size_t)(q16*16 + kt)*4 + g)*64 + lane] = pk;
        }
    } else {
        // ---- qkv GEMM, fp32-staged ----
        short* A0 = (short*)smem;          // [128][64] fp16, k-tile even
        short* A1 = A0 + 128*64;
        short* W0 = A1 + 128*64;           // [64][64]
        short* W1 = W0 + 64*64;
        int g2 = bid - 159;
        int n0 = (g2 % 12) * 64, m0 = (g2 / 12) * 128;
        int Mw = (w >> 1) * 64, Nw = (w & 1) * 32;

        v4f acc[4][2];
        #pragma unroll
        for (int mt = 0; mt < 4; ++mt)
            #pragma unroll
            for (int nt = 0; nt < 2; ++nt) acc[mt][nt] = (v4f){0,0,0,0};

        #pragma unroll 1
        for (int kt2 = 0; kt2 < 2; ++kt2) {
            __syncthreads();
            #pragma unroll
            for (int half = 0; half < 2; ++half) {
                int kt = kt2*2 + half;
                short* Ad = half ? A1 : A0;
                short* Wd = half ? W1 : W0;
                #pragma unroll
                for (int i = 0; i < 4; ++i) {
                    int rr = w*32 + i*8 + lr8;
                    const float* s = x + (size_t)(m0 + rr)*256 + kt*64 + lc8*8;
                    float4 f0 = *(const float4*)s;
                    float4 f1 = *(const float4*)(s + 4);
                    v8h hv;
                    hv[0]=(_Float16)f0.x; hv[1]=(_Float16)f0.y;
                    hv[2]=(_Float16)f0.z; hv[3]=(_Float16)f0.w;
                    hv[4]=(_Float16)f1.x; hv[5]=(_Float16)f1.y;
                    hv[6]=(_Float16)f1.z; hv[7]=(_Float16)f1.w;
                    *(v8h*)&Ad[rr*64 + ((lc8 ^ lr8) << 3)] = hv;   // rr&7 == lr8
                }
                #pragma unroll
                for (int i = 0; i < 2; ++i) {
                    int rr = w*16 + i*8 + lr8;
                    const float* s = wq + (size_t)(n0 + rr)*256 + kt*64 + lc8*8;
                    float4 f0 = *(const float4*)s;
                    float4 f1 = *(const float4*)(s + 4);
                    v8h hv;
                    hv[0]=(_Float16)f0.x; hv[1]=(_Float16)f0.y;
                    hv[2]=(_Float16)f0.z; hv[3]=(_Float16)f0.w;
                    hv[4]=(_Float16)f1.x; hv[5]=(_Float16)f1.y;
                    hv[6]=(_Float16)f1.z; hv[7]=(_Float16)f1.w;
                    *(v8h*)&Wd[rr*64 + ((lc8 ^ lr8) << 3)] = hv;
                }
            }
            __syncthreads();
            #pragma unroll
            for (int half = 0; half < 2; ++half) {
                const short* As = half ? A1 : A0;
                const short* Ws = half ? W1 : W0;
                #pragma unroll
                for (int kk = 0; kk < 2; ++kk) {
                    int cp = ((kk*4 + quad) ^ (t & 7)) << 3;
                    v8h bh8[2];
                    #pragma unroll
                    for (int nt = 0; nt < 2; ++nt)
                        bh8[nt] = *(const v8h*)&Ws[(Nw + nt*16 + t)*64 + cp];
                    #pragma unroll
                    for (int mt = 0; mt < 4; ++mt) {
                        v8h ah = *(const v8h*)&As[(Mw + mt*16 + t)*64 + cp];
                        #pragma unroll
                        for (int nt = 0; nt < 2; ++nt)
                            acc[mt][nt] = MFMAH(ah, bh8[nt], acc[mt][nt]);
                    }
                }
            }
        }

        // bias
        #pragma unroll
        for (int nt = 0; nt < 2; ++nt) {
            float bv = qkvb[n0 + Nw + nt*16 + t];
            #pragma unroll
            for (int mt = 0; mt < 4; ++mt)
                #pragma unroll
                for (int r = 0; r < 4; ++r) acc[mt][nt][r] += bv;
        }

        int which = n0 >> 8;
        if (which < 2) {
            int head = ((n0 + Nw) >> 5) & 7;
            float scale = 0.f;
            if (which == 0)
                scale = log1pf(__expf(temp[head])) * 10.0f;  // softplus*ln(1024)*log2e
            #pragma unroll
            for (int mt = 0; mt < 4; ++mt)
                #pragma unroll
                for (int r = 0; r < 4; ++r) {
                    float a0 = acc[mt][0][r], a1 = acc[mt][1][r];
                    float s = a0*a0 + a1*a1;
                    s += __shfl_xor(s, 1); s += __shfl_xor(s, 2);
                    s += __shfl_xor(s, 4); s += __shfl_xor(s, 8);
                    float inv = 1.0f / fmaxf(sqrtf(s), 1e-12f);
                    int m = m0 + Mw + mt*16 + quad*4 + r;
                    int b = m >> 10, nrow = m & 1023;
                    if (which == 0) {
                        size_t rowoff = (((size_t)b*8 + head)*1024 + nrow) * 32;
                        #pragma unroll
                        for (int nt = 0; nt < 2; ++nt) {
                            int d = nt*16 + t;
                            float val = (acc[mt][nt][r] * inv + qe[head*32 + d]) * scale;
                            qh[rowoff + d] = f2h(val);
                        }
                    } else {
                        int kk = nrow & 63;
                        int pp = (kk & 3)*16 + (kk >> 2);
                        int prow = (nrow & ~63) | pp;
                        int swk = (kk >> 3) & 3;
                        size_t rowoff = (((size_t)b*8 + head)*1024 + prow) * 32;
                        #pragma unroll
                        for (int nt = 0; nt < 2; ++nt) {
                            int d = nt*16 + t;
                            int dpos = (((d >> 3) ^ swk) << 3) | (d & 7);
                            kh[rowoff + dpos] = f2h(acc[mt][nt][r] * inv);
                        }
                    }
                }
        } else {
            // v: transpose via LDS, write vt[bh][dim][key] bf16, tile-swizzled
            __syncthreads();
            short* VT = (short*)smem;        // [64][136]
            #pragma unroll
            for (int mt = 0; mt < 4; ++mt)
                #pragma unroll
                for (int nt = 0; nt < 2; ++nt) {
                    int cl = Nw + nt*16 + t;
                    #pragma unroll
                    for (int r = 0; r < 4; ++r) {
                        int rl = Mw + mt*16 + quad*4 + r;
                        VT[cl*136 + rl] = bf_rh(acc[mt][nt][r]);
                    }
                }
            __syncthreads();
            int b = m0 >> 10;
            int keybase = m0 & 1023;
            int headbase = ((n0 - 512) >> 5) & 7;
            int cl = tid >> 2;
            int dim = cl & 31;
            int hd  = headbase + (cl >> 5);
            size_t obase = (((size_t)b*8 + hd)*32 + dim) * 1024 + keybase;
            #pragma unroll
            for (int pz = 0; pz < 4; ++pz) {
                int ci  = (tid & 3) * 4 + pz;
                int ktl = ci >> 3, c = ci & 7;
                v8s val = *(const v8s*)&VT[cl*136 + ktl*64 + c*8];
                *(v8s*)&vt[obase + ktl*64 + ((c ^ (dim & 7)) << 3)] = val;
            }
        }
    }
}

// ---------------------------------------------------------------------------
// K2 attn+proj: flash attention (round-4 body, LDS bias gather) + TICKET-FUSED
// output projection. Block remap bid = h*64 + (b*8+qt): the 8 head-blocks of
// a (b,qt) row-group have bids congruent mod 8 -> SAME XCD -> y handoff stays
// within one L2. After writing its y slice each block release-fences and
// bumps done[b*8+qt]; the 8th arriver acquire-fences and runs the 128x256
// proj tile (MFMA, bit-identical accumulation order to the old gemm_proj).
// No spinning -> deadlock-free. Non-winners exit, freeing CUs.
// ---------------------------------------------------------------------------
__global__ __launch_bounds__(512)
void attn_mfma(const short* __restrict__ qh, const short* __restrict__ kh,
               const short* __restrict__ vt,
               const unsigned long long* __restrict__ bi,
               const float* __restrict__ tblf,
               short* __restrict__ yh,
               const short* __restrict__ wph,
               const float* __restrict__ projb,
               float* __restrict__ out,
               unsigned* __restrict__ done)
{
    __shared__ __align__(16) char smem[49696];
    __shared__ unsigned wflag;
    short* Kh  = (short*)smem;           // [2][2048] fp16
    short* Vts = Kh + 4096;              // [2][2048] bf16
    short* Psb = Vts + 4096;             // [8][16][68] bf16
    float* tb  = (float*)(Psb + 8704);   // [3969] f32

    int h   = blockIdx.x >> 6;           // 0..7  (bid%8 == group parity-> same XCD per group? see below)
    int g   = blockIdx.x & 63;           // b*8 + qt ; group id for tickets
    int b   = g >> 3;
    int qt  = g & 7;
    int bh  = b*8 + h;
    int tid = threadIdx.x;
    int w    = tid >> 6;        // 0..7
    int lane = tid & 63;
    int t    = lane & 15;
    int quad = lane >> 4;
    int lr8 = lane >> 3, lc8 = lane & 7;

    // stage bias table for this head
    for (int i = tid; i < 3969; i += 512) tb[i] = tblf[h*3969 + i];

    size_t qoff = ((size_t)bh*1024 + qt*128 + w*16 + t) * 32 + quad*8;
    v8h qf = *(const v8h*)(qh + qoff);

    v4f Oacc[2] = {{0,0,0,0},{0,0,0,0}};
    float lsum[4] = {0,0,0,0};

    size_t kgbase = (size_t)bh * 32768;
    const unsigned long long* bmb = bi + (size_t)(qt*8 + w)*4096 + lane;
    int qrow0 = qt*128 + w*16 + quad*4;
    int swzS = (quad ^ ((t >> 1) & 3)) << 3;

    // stage tile 0 into buffer 0 (1 gld16 per wave: w<4 -> K, w>=4 -> V)
    if (w < 4)
        gld16(kh + kgbase + w*512 + lane*8, &Kh[w*512]);
    else
        gld16(vt + kgbase + (size_t)((w-4)*8 + lr8)*1024 + lc8*8, &Vts[(w-4)*512]);
    unsigned long long curb[4];
    #pragma unroll
    for (int gg = 0; gg < 4; ++gg) curb[gg] = bmb[gg*64];

    #pragma unroll 1
    for (int kt = 0; kt < 16; ++kt) {
        int cur = kt & 1;
        __syncthreads();   // tile loads landed; tb staged (first iter)
        unsigned long long nxtb[4];
        if (kt < 15) {
            int nkt = kt + 1, nb = cur ^ 1;
            if (w < 4)
                gld16(kh + kgbase + (size_t)nkt*2048 + w*512 + lane*8,
                      &Kh[nb*2048 + w*512]);
            else
                gld16(vt + kgbase + (size_t)((w-4)*8 + lr8)*1024 + nkt*64 + lc8*8,
                      &Vts[nb*2048 + (w-4)*512]);
            #pragma unroll
            for (int gg = 0; gg < 4; ++gg) nxtb[gg] = bmb[nkt*256 + gg*64];
        }

        // S = bias + Q K^T (fp16, 1 pass), exp2 domain; bias gathered from LDS
        v4f S[4];
        #pragma unroll
        for (int gg = 0; gg < 4; ++gg) {
            v8h kb = *(const v8h*)&Kh[cur*2048 + (gg*16 + t)*32 + swzS];
            unsigned long long cb = curb[gg];
            v4f c;
            c[0] = tb[(uint32_t)cb & 0xFFFFu];
            c[1] = tb[(uint32_t)(cb >> 16) & 0xFFFFu];
            c[2] = tb[(uint32_t)(cb >> 32) & 0xFFFFu];
            c[3] = tb[(uint32_t)(cb >> 48)];
            S[gg] = MFMAH(qf, kb, c);
        }

        // p = exp2(S); P cols are contiguous actual keys 4t+g -> packed b64
        #pragma unroll
        for (int r = 0; r < 4; ++r) {
            float p0 = EXP2(S[0][r]);
            float p1 = EXP2(S[1][r]);
            float p2 = EXP2(S[2][r]);
            float p3 = EXP2(S[3][r]);
            lsum[r] += (p0 + p1) + (p2 + p3);
            uint2 pk;
            pk.x = pack_bf_rh(p0, p1);
            pk.y = pack_bf_rh(p2, p3);
            *(uint2*)&Psb[(w*16 + quad*4 + r)*68 + t*4] = pk;
        }

        // O += P V (same-wave LDS dependency, no barrier)
        #pragma unroll
        for (int ks = 0; ks < 2; ++ks) {
            v8s pf = *(const v8s*)&Psb[(w*16 + t)*68 + ks*32 + quad*8];
            int vsw = ((ks*4 + quad) ^ (t & 7)) << 3;
            #pragma unroll
            for (int gg = 0; gg < 2; ++gg) {
                v8s vf = *(const v8s*)&Vts[cur*2048 + (gg*16 + t)*64 + vsw];
                Oacc[gg] = MFMA(pf, vf, Oacc[gg]);
            }
        }
        #pragma unroll
        for (int gg = 0; gg < 4; ++gg) curb[gg] = nxtb[gg];
    }

    // epilogue: reduce l, normalize, write swizzled fp16 y
    #pragma unroll
    for (int r = 0; r < 4; ++r) {
        float l = lsum[r];
        l += __shfl_xor(l, 1); l += __shfl_xor(l, 2);
        l += __shfl_xor(l, 4); l += __shfl_xor(l, 8);
        float inv = 1.0f / l;
        int qrow = qrow0 + r;
        int m = b*1024 + qrow;
        size_t mbase = (size_t)m * 256;
        int mk = m & 7;
        #pragma unroll
        for (int gg = 0; gg < 2; ++gg) {
            float o = Oacc[gg][r] * inv;
            int c = h*4 + gg*2 + (t >> 3);
            int chp = ((c ^ mk) << 3) | (t & 7);
            yh[mbase + chp] = f2h(o);
        }
    }

    // ---- ticket: last head-block of (b,qt) group runs the proj tile ----
    __threadfence();            // release this thread's y stores
    __syncthreads();            // whole block released
    if (tid == 0) {
        unsigned prev = __hip_atomic_fetch_add(&done[g], 1u,
                            __ATOMIC_ACQ_REL, __HIP_MEMORY_SCOPE_AGENT);
        wflag = (prev == 7u);
    }
    __syncthreads();
    if (!wflag) return;
    __threadfence();            // acquire: L1 invalidate before reading y
    __syncthreads();            // attn LDS now dead -> reuse for proj

    // proj: rows m0g..+128, all 256 cols, K=256. 2 four-wave groups run two
    // 64x64 virtual blocks at a time (4 passes); per-group single-buffered
    // LDS [64][64] A + [64][64] W; accumulation order identical to gemm_proj.
    int m0g = b*1024 + qt*128;
    int grp = w >> 2;           // 0..1
    int wl  = w & 3;
    short* Asg = (short*)smem + grp*8192;   // [64][64]
    short* Wsg = Asg + 4096;                // [64][64]
    int Mw = (wl >> 1) * 32, Nw = (wl & 1) * 32;

    #pragma unroll 1
    for (int vbp = 0; vbp < 4; ++vbp) {
        int v = vbp*2 + grp;
        int m0v = m0g + (v >> 2) * 64;
        int n0v = (v & 3) * 64;
        v4f pacc[2][2];
        #pragma unroll
        for (int mt = 0; mt < 2; ++mt)
            #pragma unroll
            for (int nt = 0; nt < 2; ++nt) pacc[mt][nt] = (v4f){0,0,0,0};

        #pragma unroll 1
        for (int kt3 = 0; kt3 < 4; ++kt3) {
            __syncthreads();
            #pragma unroll
            for (int i = 0; i < 2; ++i) {
                int rr = wl*16 + i*8 + lr8;
                gld16(yh + (size_t)(m0v + rr)*256 + kt3*64 + lc8*8, Asg + rr*64);
            }
            #pragma unroll
            for (int i = 0; i < 2; ++i) {
                int rr = wl*16 + i*8 + lr8;
                gld16(wph + (size_t)(n0v + rr)*256 + kt3*64 + lc8*8, Wsg + rr*64);
            }
            __syncthreads();
            #pragma unroll
            for (int kk = 0; kk < 2; ++kk) {
                int cp = ((kk*4 + quad) ^ (t & 7)) << 3;
                v8h bh8[2];
                #pragma unroll
                for (int nt = 0; nt < 2; ++nt)
                    bh8[nt] = *(const v8h*)&Wsg[(Nw + nt*16 + t)*64 + cp];
                #pragma unroll
                for (int mt = 0; mt < 2; ++mt) {
                    v8h ah = *(const v8h*)&Asg[(Mw + mt*16 + t)*64 + cp];
                    #pragma unroll
                    for (int nt = 0; nt < 2; ++nt)
                        pacc[mt][nt] = MFMAH(ah, bh8[nt], pacc[mt][nt]);
                }
            }
        }

        #pragma unroll
        for (int nt = 0; nt < 2; ++nt) {
            float bv = projb[n0v + Nw + nt*16 + t];
            #pragma unroll
            for (int mt = 0; mt < 2; ++mt)
                #pragma unroll
                for (int r = 0; r < 4; ++r) pacc[mt][nt][r] += bv;
        }
        #pragma unroll
        for (int mt = 0; mt < 2; ++mt)
            #pragma unroll
            for (int r = 0; r < 4; ++r) {
                int m = m0v + Mw + mt*16 + quad*4 + r;
                #pragma unroll
                for (int nt = 0; nt < 2; ++nt)
                    out[(size_t)m * 256 + n0v + Nw + nt*16 + t] = pacc[mt][nt][r];
            }
    }
}

// ---------------------------------------------------------------------------
extern "C" void kernel_launch(void* const* d_in, const int* in_sizes, int n_in,
                              void* d_out, int out_size, void* d_ws, size_t ws_size,
                              hipStream_t stream)
{
    const float* x     = (const float*)d_in[0];
    const int*   rpi   = (const int*)d_in[3];
    const float* rct   = (const float*)d_in[4];
    const float* qkvw  = (const float*)d_in[5];
    const float* qkvb  = (const float*)d_in[6];
    const float* qe    = (const float*)d_in[7];
    const float* temp  = (const float*)d_in[8];
    const float* projw = (const float*)d_in[9];
    const float* projb = (const float*)d_in[10];
    const float* fc1w  = (const float*)d_in[11];
    const float* fc1b  = (const float*)d_in[12];
    const float* fc2w  = (const float*)d_in[13];
    const float* fc2b  = (const float*)d_in[14];

    char* p = (char*)d_ws;
    float* tblf  = (float*)p;  p += 131072;
    short* y     = (short*)p;  p += 4194304;   // attn output (fp16, swizzled)
    short* wph   = (short*)p;  p += 131072;
    short* qh    = (short*)p;  p += 4194304;
    short* kh    = (short*)p;  p += 4194304;
    short* vt    = (short*)p;  p += 4194304;
    unsigned long long* bi = (unsigned long long*)p; p += 2097152;
    unsigned* done = (unsigned*)p; p += 256;
    float* out   = (float*)d_out;

    // 1) fused: qkv GEMM (fp32-staged) + CPB MLP + wp convert + rpi pack
    //    + proj-ticket zeroing
    fused_qkv<<<927, 256, 0, stream>>>(x, qkvw, projw, rct,
                                       fc1w, fc1b, fc2w, fc2b,
                                       qkvb, qe, temp, rpi,
                                       qh, kh, vt, tblf, wph, bi, done);

    // 2) attention + ticket-fused output projection (last head-block of each
    //    (b,qt) group computes the 128x256 proj tile) -> d_out
    attn_mfma<<<512, 512, 0, stream>>>(qh, kh, vt, bi, tblf, y,
                                       wph, projb, out, done);
}

// Round 6
// 203.991 us; speedup vs baseline: 1.3903x; 1.3903x over previous
//
#include <hip/hip_runtime.h>
#include <hip/hip_bf16.h>
#include <cstddef>
#include <cstdint>

typedef float v4f __attribute__((ext_vector_type(4)));
typedef short v8s __attribute__((ext_vector_type(8)));
typedef _Float16 v8h __attribute__((ext_vector_type(8)));

__device__ __forceinline__ uint32_t fbits(float x){ uint32_t u; __builtin_memcpy(&u,&x,4); return u; }
__device__ __forceinline__ float ffrom(uint32_t u){ float f; __builtin_memcpy(&f,&u,4); return f; }
// round-half-up bf16
__device__ __forceinline__ short bf_rh(float x){ return (short)((fbits(x)+0x8000u)>>16); }
__device__ __forceinline__ uint32_t pack_bf_rh(float a, float b){
    uint32_t ua = fbits(a)+0x8000u, ub = fbits(b)+0x8000u;
#if __has_builtin(__builtin_amdgcn_perm)
    return __builtin_amdgcn_perm(ub, ua, 0x07060302u);
#else
    return (ua>>16) | (ub & 0xFFFF0000u);
#endif
}
// fp16 (RNE) stored in a short
__device__ __forceinline__ short f2h(float x){ _Float16 h = (_Float16)x; short s; __builtin_memcpy(&s,&h,2); return s; }
#if __has_builtin(__builtin_amdgcn_exp2f)
#define EXP2(x) __builtin_amdgcn_exp2f(x)
#else
#define EXP2(x) exp2f(x)
#endif

__device__ __forceinline__ void gld16(const void* g, void* l) {
    __builtin_amdgcn_global_load_lds(
        (const __attribute__((address_space(1))) unsigned int*)g,
        (__attribute__((address_space(3))) unsigned int*)l, 16, 0, 0);
}
#define MFMA(a,b,c)  __builtin_amdgcn_mfma_f32_16x16x32_bf16((a),(b),(c),0,0,0)
#define MFMAH(a,b,c) __builtin_amdgcn_mfma_f32_16x16x32_f16((a),(b),(c),0,0,0)

#define LOG2E 1.4426950408889634f

// ---------------------------------------------------------------------------
// K1 fused_qkv (927 blocks x 256): round-4 structure (ticket logic removed).
//   blocks   0..62  : CPB MLP -> tblf[8][3969] (pre-scaled by log2e)
//   blocks  63..94  : proj_w fp32 -> fp16 chunk-swizzled (wph)
//   blocks  95..158 : rpi -> packed u16 indices bi[] (MFMA C-frag order)
//   blocks 159..926 : qkv GEMM TM=128 TN=64 BK=128, fp32-staged with
//                     in-register fp16 convert + write-side XOR swizzle;
//                     fused q/k/v epilogues.
// ---------------------------------------------------------------------------
__global__ __launch_bounds__(256)
void fused_qkv(const float* __restrict__ x,   const float* __restrict__ wq,
               const float* __restrict__ wp,  const float* __restrict__ rct,
               const float* __restrict__ fc1w, const float* __restrict__ fc1b,
               const float* __restrict__ fc2w, const float* __restrict__ fc2b,
               const float* __restrict__ qkvb, const float* __restrict__ qe,
               const float* __restrict__ temp, const int* __restrict__ rpi,
               short* __restrict__ qh, short* __restrict__ kh,
               short* __restrict__ vt, float* __restrict__ tblf,
               short* __restrict__ wph, unsigned long long* __restrict__ bi)
{
    __shared__ __align__(16) char smem[49152];
    int bid  = blockIdx.x;
    int tid  = threadIdx.x;
    int w    = tid >> 6;
    int lane = tid & 63;
    int t    = lane & 15;
    int quad = lane >> 4;
    int lr8  = lane >> 3, lc8 = lane & 7;

    if (bid < 63) {
        // ---- CPB MLP ----
        float* s1 = (float*)smem;      // 1024 f
        float* sb = s1 + 1024;         // 512 f
        float* s2 = sb + 512;          // 4096 f
        for (int i = tid; i < 1024; i += 256) s1[i] = fc1w[i];
        for (int i = tid; i < 512;  i += 256) sb[i] = fc1b[i];
        for (int i = tid; i < 4096; i += 256) s2[i] = fc2w[i];
        __syncthreads();
        int rl = tid >> 2, jp = tid & 3;
        bool ok = rl < 63;
        int r = bid * 63 + rl;
        float c0 = ok ? rct[2*r]   : 0.f;
        float c1 = ok ? rct[2*r+1] : 0.f;
        float a[8] = {0,0,0,0,0,0,0,0};
        int j0 = jp * 128;
        #pragma unroll 4
        for (int j = j0; j < j0 + 128; ++j) {
            float hv = fmaxf(c0*s1[2*j] + c1*s1[2*j+1] + sb[j], 0.0f);
            #pragma unroll
            for (int hh = 0; hh < 8; ++hh) a[hh] += hv * s2[hh*512 + j];
        }
        #pragma unroll
        for (int hh = 0; hh < 8; ++hh) {
            a[hh] += __shfl_xor(a[hh], 1);
            a[hh] += __shfl_xor(a[hh], 2);
        }
        if (ok && jp == 0) {
            #pragma unroll
            for (int hh = 0; hh < 8; ++hh)
                tblf[hh*3969 + r] = (a[hh] + fc2b[hh]) * LOG2E;  // pre-scaled
        }
    } else if (bid < 95) {
        // ---- proj_w fp32 -> fp16 swizzled ----
        int base8 = (bid - 63) * 256;
        int e0 = (base8 + tid) * 8;
        int m  = e0 >> 8;
        int k  = e0 & 255;
        int kt = k >> 6, c = (k >> 3) & 7;
        float4 f0 = *(const float4*)(wp + e0);
        float4 f1 = *(const float4*)(wp + e0 + 4);
        float v[8] = {f0.x,f0.y,f0.z,f0.w,f1.x,f1.y,f1.z,f1.w};
        v8s hi;
        #pragma unroll
        for (int j = 0; j < 8; ++j) hi[j] = f2h(v[j]);
        int dst = m*256 + kt*64 + ((c ^ (m & 7)) << 3);
        *(v8s*)&wph[dst] = hi;
    } else if (bid < 159) {
        // ---- rpi -> packed u16 index table, MFMA C-frag order ----
        int q16 = bid - 95;            // 0..63 (16-row group)
        int grp = tid >> 6;            // 0..3
        #pragma unroll 1
        for (int c = 0; c < 16; ++c) {
            int combo = grp*16 + c;
            int kt = combo >> 2, g = combo & 3;
            unsigned long long pk = 0;
            #pragma unroll
            for (int r = 0; r < 4; ++r) {
                int idx = rpi[(size_t)(q16*16 + quad*4 + r)*1024 + kt*64 + 4*t + g];
                pk |= (unsigned long long)(idx & 0xFFFF) << (16*r);
            }
            bi[((size_t)(q16*16 + kt)*4 + g)*64 + lane] = pk;
        }
    } else {
        // ---- qkv GEMM, fp32-staged ----
        short* A0 = (short*)smem;          // [128][64] fp16, k-tile even
        short* A1 = A0 + 128*64;
        short* W0 = A1 + 128*64;           // [64][64]
        short* W1 = W0 + 64*64;
        int g2 = bid - 159;
        int n0 = (g2 % 12) * 64, m0 = (g2 / 12) * 128;
        int Mw = (w >> 1) * 64, Nw = (w & 1) * 32;

        v4f acc[4][2];
        #pragma unroll
        for (int mt = 0; mt < 4; ++mt)
            #pragma unroll
            for (int nt = 0; nt < 2; ++nt) acc[mt][nt] = (v4f){0,0,0,0};

        #pragma unroll 1
        for (int kt2 = 0; kt2 < 2; ++kt2) {
            __syncthreads();
            #pragma unroll
            for (int half = 0; half < 2; ++half) {
                int kt = kt2*2 + half;
                short* Ad = half ? A1 : A0;
                short* Wd = half ? W1 : W0;
                #pragma unroll
                for (int i = 0; i < 4; ++i) {
                    int rr = w*32 + i*8 + lr8;
                    const float* s = x + (size_t)(m0 + rr)*256 + kt*64 + lc8*8;
                    float4 f0 = *(const float4*)s;
                    float4 f1 = *(const float4*)(s + 4);
                    v8h hv;
                    hv[0]=(_Float16)f0.x; hv[1]=(_Float16)f0.y;
                    hv[2]=(_Float16)f0.z; hv[3]=(_Float16)f0.w;
                    hv[4]=(_Float16)f1.x; hv[5]=(_Float16)f1.y;
                    hv[6]=(_Float16)f1.z; hv[7]=(_Float16)f1.w;
                    *(v8h*)&Ad[rr*64 + ((lc8 ^ lr8) << 3)] = hv;   // rr&7 == lr8
                }
                #pragma unroll
                for (int i = 0; i < 2; ++i) {
                    int rr = w*16 + i*8 + lr8;
                    const float* s = wq + (size_t)(n0 + rr)*256 + kt*64 + lc8*8;
                    float4 f0 = *(const float4*)s;
                    float4 f1 = *(const float4*)(s + 4);
                    v8h hv;
                    hv[0]=(_Float16)f0.x; hv[1]=(_Float16)f0.y;
                    hv[2]=(_Float16)f0.z; hv[3]=(_Float16)f0.w;
                    hv[4]=(_Float16)f1.x; hv[5]=(_Float16)f1.y;
                    hv[6]=(_Float16)f1.z; hv[7]=(_Float16)f1.w;
                    *(v8h*)&Wd[rr*64 + ((lc8 ^ lr8) << 3)] = hv;
                }
            }
            __syncthreads();
            #pragma unroll
            for (int half = 0; half < 2; ++half) {
                const short* As = half ? A1 : A0;
                const short* Ws = half ? W1 : W0;
                #pragma unroll
                for (int kk = 0; kk < 2; ++kk) {
                    int cp = ((kk*4 + quad) ^ (t & 7)) << 3;
                    v8h bh8[2];
                    #pragma unroll
                    for (int nt = 0; nt < 2; ++nt)
                        bh8[nt] = *(const v8h*)&Ws[(Nw + nt*16 + t)*64 + cp];
                    #pragma unroll
                    for (int mt = 0; mt < 4; ++mt) {
                        v8h ah = *(const v8h*)&As[(Mw + mt*16 + t)*64 + cp];
                        #pragma unroll
                        for (int nt = 0; nt < 2; ++nt)
                            acc[mt][nt] = MFMAH(ah, bh8[nt], acc[mt][nt]);
                    }
                }
            }
        }

        // bias
        #pragma unroll
        for (int nt = 0; nt < 2; ++nt) {
            float bv = qkvb[n0 + Nw + nt*16 + t];
            #pragma unroll
            for (int mt = 0; mt < 4; ++mt)
                #pragma unroll
                for (int r = 0; r < 4; ++r) acc[mt][nt][r] += bv;
        }

        int which = n0 >> 8;
        if (which < 2) {
            int head = ((n0 + Nw) >> 5) & 7;
            float scale = 0.f;
            if (which == 0)
                scale = log1pf(__expf(temp[head])) * 10.0f;  // softplus*ln(1024)*log2e
            #pragma unroll
            for (int mt = 0; mt < 4; ++mt)
                #pragma unroll
                for (int r = 0; r < 4; ++r) {
                    float a0 = acc[mt][0][r], a1 = acc[mt][1][r];
                    float s = a0*a0 + a1*a1;
                    s += __shfl_xor(s, 1); s += __shfl_xor(s, 2);
                    s += __shfl_xor(s, 4); s += __shfl_xor(s, 8);
                    float inv = 1.0f / fmaxf(sqrtf(s), 1e-12f);
                    int m = m0 + Mw + mt*16 + quad*4 + r;
                    int b = m >> 10, nrow = m & 1023;
                    if (which == 0) {
                        size_t rowoff = (((size_t)b*8 + head)*1024 + nrow) * 32;
                        #pragma unroll
                        for (int nt = 0; nt < 2; ++nt) {
                            int d = nt*16 + t;
                            float val = (acc[mt][nt][r] * inv + qe[head*32 + d]) * scale;
                            qh[rowoff + d] = f2h(val);
                        }
                    } else {
                        int kk = nrow & 63;
                        int pp = (kk & 3)*16 + (kk >> 2);
                        int prow = (nrow & ~63) | pp;
                        int swk = (kk >> 3) & 3;
                        size_t rowoff = (((size_t)b*8 + head)*1024 + prow) * 32;
                        #pragma unroll
                        for (int nt = 0; nt < 2; ++nt) {
                            int d = nt*16 + t;
                            int dpos = (((d >> 3) ^ swk) << 3) | (d & 7);
                            kh[rowoff + dpos] = f2h(acc[mt][nt][r] * inv);
                        }
                    }
                }
        } else {
            // v: transpose via LDS, write vt[bh][dim][key] bf16, tile-swizzled
            __syncthreads();
            short* VT = (short*)smem;        // [64][136]
            #pragma unroll
            for (int mt = 0; mt < 4; ++mt)
                #pragma unroll
                for (int nt = 0; nt < 2; ++nt) {
                    int cl = Nw + nt*16 + t;
                    #pragma unroll
                    for (int r = 0; r < 4; ++r) {
                        int rl = Mw + mt*16 + quad*4 + r;
                        VT[cl*136 + rl] = bf_rh(acc[mt][nt][r]);
                    }
                }
            __syncthreads();
            int b = m0 >> 10;
            int keybase = m0 & 1023;
            int headbase = ((n0 - 512) >> 5) & 7;
            int cl = tid >> 2;
            int dim = cl & 31;
            int hd  = headbase + (cl >> 5);
            size_t obase = (((size_t)b*8 + hd)*32 + dim) * 1024 + keybase;
            #pragma unroll
            for (int pz = 0; pz < 4; ++pz) {
                int ci  = (tid & 3) * 4 + pz;
                int ktl = ci >> 3, c = ci & 7;
                v8s val = *(const v8s*)&VT[cl*136 + ktl*64 + c*8];
                *(v8s*)&vt[obase + ktl*64 + ((c ^ (dim & 7)) << 3)] = val;
            }
        }
    }
}

// ---------------------------------------------------------------------------
// K2 attn: 4-wave / 64-row Q-tile / 1024 blocks (4-6 blocks/CU vs 2 for the
// 8-wave version -> latency-bound per-tile {gld16, vmcnt-drain barrier, short
// compute} chains overlap across blocks). Row layout identical to round-3
// mega phase 2 (correctness-proven). Bias: f32 gathered DIRECTLY from global
// tblf (L2-resident 127 KB) via packed u16 indices, with next-tile value
// prefetch (gathers in flight during current tile's MFMA) — removes the
// 15.9 KB LDS table and its bank conflicts. LDS = 25 KB/block.
// ---------------------------------------------------------------------------
__global__ __launch_bounds__(256)
void attn_mfma(const short* __restrict__ qh, const short* __restrict__ kh,
               const short* __restrict__ vt,
               const unsigned long long* __restrict__ bi,
               const float* __restrict__ tblf,
               short* __restrict__ yh)
{
    __shared__ __align__(16) short Kh[2][2048];    // [64][32] fp16 per buf
    __shared__ __align__(16) short Vts[2][2048];   // [32][64] bf16 per buf
    __shared__ __align__(16) short Psb[4*16*68];   // per-wave P (bf16)

    int bh  = blockIdx.x & 63;   // bid%8 == h (XCD-aligned)
    int qt2 = blockIdx.x >> 6;   // 0..15
    int h   = bh & 7;
    int b   = bh >> 3;
    int tid = threadIdx.x;
    int w    = tid >> 6;        // 0..3
    int lane = tid & 63;
    int t    = lane & 15;
    int quad = lane >> 4;
    int lr8 = lane >> 3, lc8 = lane & 7;

    size_t qoff = ((size_t)bh*1024 + qt2*64 + w*16 + t) * 32 + quad*8;
    v8h qf = *(const v8h*)(qh + qoff);

    v4f Oacc[2] = {{0,0,0,0},{0,0,0,0}};
    float lsum[4] = {0,0,0,0};

    size_t kgbase = (size_t)bh * 32768;
    const unsigned long long* bmb = bi + (size_t)(qt2*4 + w)*4096 + lane;
    const float* tbg = tblf + h*3969;
    int qrow0 = qt2*64 + w*16 + quad*4;
    int swzS = (quad ^ ((t >> 1) & 3)) << 3;

    // stage tile 0 into buffer 0 (2 gld16 per wave: w<2 -> K, w>=2 -> V)
    if (w < 2) {
        gld16(kh + kgbase + (w*2+0)*512 + lane*8, &Kh[0][(w*2+0)*512]);
        gld16(kh + kgbase + (w*2+1)*512 + lane*8, &Kh[0][(w*2+1)*512]);
    } else {
        int v0 = w - 2;
        gld16(vt + kgbase + (size_t)(v0*16 + lr8)*1024 + lc8*8,     &Vts[0][(v0*2+0)*512]);
        gld16(vt + kgbase + (size_t)(v0*16 + 8 + lr8)*1024 + lc8*8, &Vts[0][(v0*2+1)*512]);
    }
    // gather bias values for tile 0 (global, L2-resident)
    v4f curc[4];
    #pragma unroll
    for (int g = 0; g < 4; ++g) {
        unsigned long long cb = bmb[g*64];
        curc[g][0] = tbg[(uint32_t)cb & 0xFFFFu];
        curc[g][1] = tbg[(uint32_t)(cb >> 16) & 0xFFFFu];
        curc[g][2] = tbg[(uint32_t)(cb >> 32) & 0xFFFFu];
        curc[g][3] = tbg[(uint32_t)(cb >> 48)];
    }

    #pragma unroll 1
    for (int kt = 0; kt < 16; ++kt) {
        int cur = kt & 1;
        __syncthreads();   // prior tile's loads landed; prior reads done
        v4f nxtc[4];
        if (kt < 15) {
            int nkt = kt + 1, nb = cur ^ 1;
            if (w < 2) {
                gld16(kh + kgbase + (size_t)nkt*2048 + (w*2+0)*512 + lane*8,
                      &Kh[nb][(w*2+0)*512]);
                gld16(kh + kgbase + (size_t)nkt*2048 + (w*2+1)*512 + lane*8,
                      &Kh[nb][(w*2+1)*512]);
            } else {
                int v0 = w - 2;
                gld16(vt + kgbase + (size_t)(v0*16 + lr8)*1024 + nkt*64 + lc8*8,
                      &Vts[nb][(v0*2+0)*512]);
                gld16(vt + kgbase + (size_t)(v0*16 + 8 + lr8)*1024 + nkt*64 + lc8*8,
                      &Vts[nb][(v0*2+1)*512]);
            }
            // prefetch next tile's bias values (latency hides under MFMA below)
            #pragma unroll
            for (int g = 0; g < 4; ++g) {
                unsigned long long cb = bmb[nkt*256 + g*64];
                nxtc[g][0] = tbg[(uint32_t)cb & 0xFFFFu];
                nxtc[g][1] = tbg[(uint32_t)(cb >> 16) & 0xFFFFu];
                nxtc[g][2] = tbg[(uint32_t)(cb >> 32) & 0xFFFFu];
                nxtc[g][3] = tbg[(uint32_t)(cb >> 48)];
            }
        }

        // S = bias + Q K^T (fp16, 1 pass), exp2 domain
        v4f S[4];
        #pragma unroll
        for (int g = 0; g < 4; ++g) {
            v8h kb = *(const v8h*)&Kh[cur][(g*16 + t)*32 + swzS];
            S[g] = MFMAH(qf, kb, curc[g]);
        }

        // p = exp2(S); P cols are contiguous actual keys 4t+g -> packed b64
        #pragma unroll
        for (int r = 0; r < 4; ++r) {
            float p0 = EXP2(S[0][r]);
            float p1 = EXP2(S[1][r]);
            float p2 = EXP2(S[2][r]);
            float p3 = EXP2(S[3][r]);
            lsum[r] += (p0 + p1) + (p2 + p3);
            uint2 pk;
            pk.x = pack_bf_rh(p0, p1);
            pk.y = pack_bf_rh(p2, p3);
            *(uint2*)&Psb[(w*16 + quad*4 + r)*68 + t*4] = pk;
        }

        // O += P V (same-wave LDS dependency, no barrier)
        #pragma unroll
        for (int ks = 0; ks < 2; ++ks) {
            v8s pf = *(const v8s*)&Psb[(w*16 + t)*68 + ks*32 + quad*8];
            int vsw = ((ks*4 + quad) ^ (t & 7)) << 3;
            #pragma unroll
            for (int g = 0; g < 2; ++g) {
                v8s vf = *(const v8s*)&Vts[cur][(g*16 + t)*64 + vsw];
                Oacc[g] = MFMA(pf, vf, Oacc[g]);
            }
        }
        #pragma unroll
        for (int g = 0; g < 4; ++g) curc[g] = nxtc[g];
    }

    // epilogue: reduce l, normalize, write swizzled fp16 y
    #pragma unroll
    for (int r = 0; r < 4; ++r) {
        float l = lsum[r];
        l += __shfl_xor(l, 1); l += __shfl_xor(l, 2);
        l += __shfl_xor(l, 4); l += __shfl_xor(l, 8);
        float inv = 1.0f / l;
        int qrow = qrow0 + r;
        int m = b*1024 + qrow;
        size_t mbase = (size_t)m * 256;
        int mk = m & 7;
        #pragma unroll
        for (int g = 0; g < 2; ++g) {
            float o = Oacc[g][r] * inv;
            int c = h*4 + g*2 + (t >> 3);
            int chp = ((c ^ mk) << 3) | (t & 7);
            yh[mbase + chp] = f2h(o);
        }
    }
}

// ---------------------------------------------------------------------------
// K3 output projection: fp16 1-pass MFMA GEMM, TM=64 TN=64, BK=128.
// ---------------------------------------------------------------------------
__global__ __launch_bounds__(256)
void gemm_proj(const short* __restrict__ Ah_g, const short* __restrict__ Wh_g,
               const float* __restrict__ bias, float* __restrict__ C, int N)
{
    __shared__ __align__(16) short As[2][4096];   // [64][64] fp16 per buf
    __shared__ __align__(16) short Ws[2][4096];

    int tid  = threadIdx.x;
    int w    = tid >> 6;
    int lane = tid & 63;
    int t    = lane & 15;
    int quad = lane >> 4;
    int m0 = blockIdx.y * 64, n0 = blockIdx.x * 64;
    int Mw = (w >> 1) * 32, Nw = (w & 1) * 32;

    v4f acc[2][2];
    #pragma unroll
    for (int mt = 0; mt < 2; ++mt)
        #pragma unroll
        for (int nt = 0; nt < 2; ++nt) acc[mt][nt] = (v4f){0,0,0,0};

    int lr8 = lane >> 3, lc8 = lane & 7;
    #pragma unroll 1
    for (int kt2 = 0; kt2 < 2; ++kt2) {
        __syncthreads();
        #pragma unroll
        for (int half = 0; half < 2; ++half) {
            int kt = kt2*2 + half;
            #pragma unroll
            for (int i = 0; i < 2; ++i) {
                size_t grow = (size_t)(m0 + w*16 + i*8 + lr8) * 256 + kt*64 + lc8*8;
                gld16(Ah_g + grow, &As[half][(w*16 + i*8) * 64]);
            }
            #pragma unroll
            for (int i = 0; i < 2; ++i) {
                size_t grow = (size_t)(n0 + w*16 + i*8 + lr8) * 256 + kt*64 + lc8*8;
                gld16(Wh_g + grow, &Ws[half][(w*16 + i*8) * 64]);
            }
        }
        __syncthreads();
        #pragma unroll
        for (int half = 0; half < 2; ++half) {
            #pragma unroll
            for (int kk = 0; kk < 2; ++kk) {
                int cp = ((kk*4 + quad) ^ (t & 7)) << 3;
                v8h bh8[2];
                #pragma unroll
                for (int nt = 0; nt < 2; ++nt)
                    bh8[nt] = *(const v8h*)&Ws[half][(Nw + nt*16 + t)*64 + cp];
                #pragma unroll
                for (int mt = 0; mt < 2; ++mt) {
                    v8h ah = *(const v8h*)&As[half][(Mw + mt*16 + t)*64 + cp];
                    #pragma unroll
                    for (int nt = 0; nt < 2; ++nt)
                        acc[mt][nt] = MFMAH(ah, bh8[nt], acc[mt][nt]);
                }
            }
        }
    }

    #pragma unroll
    for (int nt = 0; nt < 2; ++nt) {
        float bv = bias[n0 + Nw + nt*16 + t];
        #pragma unroll
        for (int mt = 0; mt < 2; ++mt)
            #pragma unroll
            for (int r = 0; r < 4; ++r) acc[mt][nt][r] += bv;
    }
    #pragma unroll
    for (int mt = 0; mt < 2; ++mt)
        #pragma unroll
        for (int r = 0; r < 4; ++r) {
            int m = m0 + Mw + mt*16 + quad*4 + r;
            #pragma unroll
            for (int nt = 0; nt < 2; ++nt)
                C[(size_t)m * N + n0 + Nw + nt*16 + t] = acc[mt][nt][r];
        }
}

// ---------------------------------------------------------------------------
extern "C" void kernel_launch(void* const* d_in, const int* in_sizes, int n_in,
                              void* d_out, int out_size, void* d_ws, size_t ws_size,
                              hipStream_t stream)
{
    const float* x     = (const float*)d_in[0];
    const int*   rpi   = (const int*)d_in[3];
    const float* rct   = (const float*)d_in[4];
    const float* qkvw  = (const float*)d_in[5];
    const float* qkvb  = (const float*)d_in[6];
    const float* qe    = (const float*)d_in[7];
    const float* temp  = (const float*)d_in[8];
    const float* projw = (const float*)d_in[9];
    const float* projb = (const float*)d_in[10];
    const float* fc1w  = (const float*)d_in[11];
    const float* fc1b  = (const float*)d_in[12];
    const float* fc2w  = (const float*)d_in[13];
    const float* fc2b  = (const float*)d_in[14];

    char* p = (char*)d_ws;
    float* tblf  = (float*)p;  p += 131072;
    short* y     = (short*)p;  p += 4194304;   // attn output (fp16, swizzled)
    short* wph   = (short*)p;  p += 131072;
    short* qh    = (short*)p;  p += 4194304;
    short* kh    = (short*)p;  p += 4194304;
    short* vt    = (short*)p;  p += 4194304;
    unsigned long long* bi = (unsigned long long*)p; p += 2097152;
    float* out   = (float*)d_out;

    // 1) fused: qkv GEMM (fp32-staged) + CPB MLP + wp convert + rpi pack
    fused_qkv<<<927, 256, 0, stream>>>(x, qkvw, projw, rct,
                                       fc1w, fc1b, fc2w, fc2b,
                                       qkvb, qe, temp, rpi,
                                       qh, kh, vt, tblf, wph, bi);

    // 2) attention: 4-wave / 64-row Q-tiles / 1024 blocks, global bias gather
    attn_mfma<<<1024, 256, 0, stream>>>(qh, kh, vt, bi, tblf, y);

    // 3) output projection -> d_out (fp32)
    dim3 g2(256/64, 8192/64);
    gemm_proj<<<g2, 256, 0, stream>>>(y, wph, projb, out, 256);
}

// Round 7
// 150.558 us; speedup vs baseline: 1.8837x; 1.3549x over previous
//
#include <hip/hip_runtime.h>
#include <hip/hip_bf16.h>
#include <cstddef>
#include <cstdint>

typedef float v4f __attribute__((ext_vector_type(4)));
typedef short v8s __attribute__((ext_vector_type(8)));
typedef _Float16 v8h __attribute__((ext_vector_type(8)));

__device__ __forceinline__ uint32_t fbits(float x){ uint32_t u; __builtin_memcpy(&u,&x,4); return u; }
__device__ __forceinline__ float ffrom(uint32_t u){ float f; __builtin_memcpy(&f,&u,4); return f; }
// round-half-up bf16
__device__ __forceinline__ short bf_rh(float x){ return (short)((fbits(x)+0x8000u)>>16); }
__device__ __forceinline__ uint32_t pack_bf_rh(float a, float b){
    uint32_t ua = fbits(a)+0x8000u, ub = fbits(b)+0x8000u;
#if __has_builtin(__builtin_amdgcn_perm)
    return __builtin_amdgcn_perm(ub, ua, 0x07060302u);
#else
    return (ua>>16) | (ub & 0xFFFF0000u);
#endif
}
// fp16 (RNE) stored in a short
__device__ __forceinline__ short f2h(float x){ _Float16 h = (_Float16)x; short s; __builtin_memcpy(&s,&h,2); return s; }
#if __has_builtin(__builtin_amdgcn_exp2f)
#define EXP2(x) __builtin_amdgcn_exp2f(x)
#else
#define EXP2(x) exp2f(x)
#endif

__device__ __forceinline__ void gld16(const void* g, void* l) {
    __builtin_amdgcn_global_load_lds(
        (const __attribute__((address_space(1))) unsigned int*)g,
        (__attribute__((address_space(3))) unsigned int*)l, 16, 0, 0);
}
#define MFMA(a,b,c)  __builtin_amdgcn_mfma_f32_16x16x32_bf16((a),(b),(c),0,0,0)
#define MFMAH(a,b,c) __builtin_amdgcn_mfma_f32_16x16x32_f16((a),(b),(c),0,0,0)

#define LOG2E 1.4426950408889634f

// ---------------------------------------------------------------------------
// K1 fused_qkv (927 blocks x 256): identical to round 6 except the CPB MLP
// writes a bf16 bias table (stride 4096 per head, 16B-aligned for v8s
// staging) instead of f32 — the attention kernel now gathers bias from an
// LDS bf16 copy (round-4 mechanism; bf16 precision already validated by the
// rounds-0/1 bf16 biasM at absmax 0.00195).
//   blocks   0..62  : CPB MLP -> tbl_bf[8][4096] bf16 (pre-scaled by log2e)
//   blocks  63..94  : proj_w fp32 -> fp16 chunk-swizzled (wph)
//   blocks  95..158 : rpi -> packed u16 indices bi[] (MFMA C-frag order)
//   blocks 159..926 : qkv GEMM TM=128 TN=64 BK=128, fp32-staged with
//                     in-register fp16 convert + write-side XOR swizzle;
//                     fused q/k/v epilogues.
// ---------------------------------------------------------------------------
__global__ __launch_bounds__(256)
void fused_qkv(const float* __restrict__ x,   const float* __restrict__ wq,
               const float* __restrict__ wp,  const float* __restrict__ rct,
               const float* __restrict__ fc1w, const float* __restrict__ fc1b,
               const float* __restrict__ fc2w, const float* __restrict__ fc2b,
               const float* __restrict__ qkvb, const float* __restrict__ qe,
               const float* __restrict__ temp, const int* __restrict__ rpi,
               short* __restrict__ qh, short* __restrict__ kh,
               short* __restrict__ vt, unsigned short* __restrict__ tbl_bf,
               short* __restrict__ wph, unsigned long long* __restrict__ bi)
{
    __shared__ __align__(16) char smem[49152];
    int bid  = blockIdx.x;
    int tid  = threadIdx.x;
    int w    = tid >> 6;
    int lane = tid & 63;
    int t    = lane & 15;
    int quad = lane >> 4;
    int lr8  = lane >> 3, lc8 = lane & 7;

    if (bid < 63) {
        // ---- CPB MLP -> bf16 table ----
        float* s1 = (float*)smem;      // 1024 f
        float* sb = s1 + 1024;         // 512 f
        float* s2 = sb + 512;          // 4096 f
        for (int i = tid; i < 1024; i += 256) s1[i] = fc1w[i];
        for (int i = tid; i < 512;  i += 256) sb[i] = fc1b[i];
        for (int i = tid; i < 4096; i += 256) s2[i] = fc2w[i];
        __syncthreads();
        int rl = tid >> 2, jp = tid & 3;
        bool ok = rl < 63;
        int r = bid * 63 + rl;
        float c0 = ok ? rct[2*r]   : 0.f;
        float c1 = ok ? rct[2*r+1] : 0.f;
        float a[8] = {0,0,0,0,0,0,0,0};
        int j0 = jp * 128;
        #pragma unroll 4
        for (int j = j0; j < j0 + 128; ++j) {
            float hv = fmaxf(c0*s1[2*j] + c1*s1[2*j+1] + sb[j], 0.0f);
            #pragma unroll
            for (int hh = 0; hh < 8; ++hh) a[hh] += hv * s2[hh*512 + j];
        }
        #pragma unroll
        for (int hh = 0; hh < 8; ++hh) {
            a[hh] += __shfl_xor(a[hh], 1);
            a[hh] += __shfl_xor(a[hh], 2);
        }
        if (ok && jp == 0) {
            #pragma unroll
            for (int hh = 0; hh < 8; ++hh)
                tbl_bf[hh*4096 + r] =
                    (unsigned short)bf_rh((a[hh] + fc2b[hh]) * LOG2E);
        }
    } else if (bid < 95) {
        // ---- proj_w fp32 -> fp16 swizzled ----
        int base8 = (bid - 63) * 256;
        int e0 = (base8 + tid) * 8;
        int m  = e0 >> 8;
        int k  = e0 & 255;
        int kt = k >> 6, c = (k >> 3) & 7;
        float4 f0 = *(const float4*)(wp + e0);
        float4 f1 = *(const float4*)(wp + e0 + 4);
        float v[8] = {f0.x,f0.y,f0.z,f0.w,f1.x,f1.y,f1.z,f1.w};
        v8s hi;
        #pragma unroll
        for (int j = 0; j < 8; ++j) hi[j] = f2h(v[j]);
        int dst = m*256 + kt*64 + ((c ^ (m & 7)) << 3);
        *(v8s*)&wph[dst] = hi;
    } else if (bid < 159) {
        // ---- rpi -> packed u16 index table, MFMA C-frag order ----
        int q16 = bid - 95;            // 0..63 (16-row group)
        int grp = tid >> 6;            // 0..3
        #pragma unroll 1
        for (int c = 0; c < 16; ++c) {
            int combo = grp*16 + c;
            int kt = combo >> 2, g = combo & 3;
            unsigned long long pk = 0;
            #pragma unroll
            for (int r = 0; r < 4; ++r) {
                int idx = rpi[(size_t)(q16*16 + quad*4 + r)*1024 + kt*64 + 4*t + g];
                pk |= (unsigned long long)(idx & 0xFFFF) << (16*r);
            }
            bi[((size_t)(q16*16 + kt)*4 + g)*64 + lane] = pk;
        }
    } else {
        // ---- qkv GEMM, fp32-staged ----
        short* A0 = (short*)smem;          // [128][64] fp16, k-tile even
        short* A1 = A0 + 128*64;
        short* W0 = A1 + 128*64;           // [64][64]
        short* W1 = W0 + 64*64;
        int g2 = bid - 159;
        int n0 = (g2 % 12) * 64, m0 = (g2 / 12) * 128;
        int Mw = (w >> 1) * 64, Nw = (w & 1) * 32;

        v4f acc[4][2];
        #pragma unroll
        for (int mt = 0; mt < 4; ++mt)
            #pragma unroll
            for (int nt = 0; nt < 2; ++nt) acc[mt][nt] = (v4f){0,0,0,0};

        #pragma unroll 1
        for (int kt2 = 0; kt2 < 2; ++kt2) {
            __syncthreads();
            #pragma unroll
            for (int half = 0; half < 2; ++half) {
                int kt = kt2*2 + half;
                short* Ad = half ? A1 : A0;
                short* Wd = half ? W1 : W0;
                #pragma unroll
                for (int i = 0; i < 4; ++i) {
                    int rr = w*32 + i*8 + lr8;
                    const float* s = x + (size_t)(m0 + rr)*256 + kt*64 + lc8*8;
                    float4 f0 = *(const float4*)s;
                    float4 f1 = *(const float4*)(s + 4);
                    v8h hv;
                    hv[0]=(_Float16)f0.x; hv[1]=(_Float16)f0.y;
                    hv[2]=(_Float16)f0.z; hv[3]=(_Float16)f0.w;
                    hv[4]=(_Float16)f1.x; hv[5]=(_Float16)f1.y;
                    hv[6]=(_Float16)f1.z; hv[7]=(_Float16)f1.w;
                    *(v8h*)&Ad[rr*64 + ((lc8 ^ lr8) << 3)] = hv;   // rr&7 == lr8
                }
                #pragma unroll
                for (int i = 0; i < 2; ++i) {
                    int rr = w*16 + i*8 + lr8;
                    const float* s = wq + (size_t)(n0 + rr)*256 + kt*64 + lc8*8;
                    float4 f0 = *(const float4*)s;
                    float4 f1 = *(const float4*)(s + 4);
                    v8h hv;
                    hv[0]=(_Float16)f0.x; hv[1]=(_Float16)f0.y;
                    hv[2]=(_Float16)f0.z; hv[3]=(_Float16)f0.w;
                    hv[4]=(_Float16)f1.x; hv[5]=(_Float16)f1.y;
                    hv[6]=(_Float16)f1.z; hv[7]=(_Float16)f1.w;
                    *(v8h*)&Wd[rr*64 + ((lc8 ^ lr8) << 3)] = hv;
                }
            }
            __syncthreads();
            #pragma unroll
            for (int half = 0; half < 2; ++half) {
                const short* As = half ? A1 : A0;
                const short* Ws = half ? W1 : W0;
                #pragma unroll
                for (int kk = 0; kk < 2; ++kk) {
                    int cp = ((kk*4 + quad) ^ (t & 7)) << 3;
                    v8h bh8[2];
                    #pragma unroll
                    for (int nt = 0; nt < 2; ++nt)
                        bh8[nt] = *(const v8h*)&Ws[(Nw + nt*16 + t)*64 + cp];
                    #pragma unroll
                    for (int mt = 0; mt < 4; ++mt) {
                        v8h ah = *(const v8h*)&As[(Mw + mt*16 + t)*64 + cp];
                        #pragma unroll
                        for (int nt = 0; nt < 2; ++nt)
                            acc[mt][nt] = MFMAH(ah, bh8[nt], acc[mt][nt]);
                    }
                }
            }
        }

        // bias
        #pragma unroll
        for (int nt = 0; nt < 2; ++nt) {
            float bv = qkvb[n0 + Nw + nt*16 + t];
            #pragma unroll
            for (int mt = 0; mt < 4; ++mt)
                #pragma unroll
                for (int r = 0; r < 4; ++r) acc[mt][nt][r] += bv;
        }

        int which = n0 >> 8;
        if (which < 2) {
            int head = ((n0 + Nw) >> 5) & 7;
            float scale = 0.f;
            if (which == 0)
                scale = log1pf(__expf(temp[head])) * 10.0f;  // softplus*ln(1024)*log2e
            #pragma unroll
            for (int mt = 0; mt < 4; ++mt)
                #pragma unroll
                for (int r = 0; r < 4; ++r) {
                    float a0 = acc[mt][0][r], a1 = acc[mt][1][r];
                    float s = a0*a0 + a1*a1;
                    s += __shfl_xor(s, 1); s += __shfl_xor(s, 2);
                    s += __shfl_xor(s, 4); s += __shfl_xor(s, 8);
                    float inv = 1.0f / fmaxf(sqrtf(s), 1e-12f);
                    int m = m0 + Mw + mt*16 + quad*4 + r;
                    int b = m >> 10, nrow = m & 1023;
                    if (which == 0) {
                        size_t rowoff = (((size_t)b*8 + head)*1024 + nrow) * 32;
                        #pragma unroll
                        for (int nt = 0; nt < 2; ++nt) {
                            int d = nt*16 + t;
                            float val = (acc[mt][nt][r] * inv + qe[head*32 + d]) * scale;
                            qh[rowoff + d] = f2h(val);
                        }
                    } else {
                        int kk = nrow & 63;
                        int pp = (kk & 3)*16 + (kk >> 2);
                        int prow = (nrow & ~63) | pp;
                        int swk = (kk >> 3) & 3;
                        size_t rowoff = (((size_t)b*8 + head)*1024 + prow) * 32;
                        #pragma unroll
                        for (int nt = 0; nt < 2; ++nt) {
                            int d = nt*16 + t;
                            int dpos = (((d >> 3) ^ swk) << 3) | (d & 7);
                            kh[rowoff + dpos] = f2h(acc[mt][nt][r] * inv);
                        }
                    }
                }
        } else {
            // v: transpose via LDS, write vt[bh][dim][key] bf16, tile-swizzled
            __syncthreads();
            short* VT = (short*)smem;        // [64][136]
            #pragma unroll
            for (int mt = 0; mt < 4; ++mt)
                #pragma unroll
                for (int nt = 0; nt < 2; ++nt) {
                    int cl = Nw + nt*16 + t;
                    #pragma unroll
                    for (int r = 0; r < 4; ++r) {
                        int rl = Mw + mt*16 + quad*4 + r;
                        VT[cl*136 + rl] = bf_rh(acc[mt][nt][r]);
                    }
                }
            __syncthreads();
            int b = m0 >> 10;
            int keybase = m0 & 1023;
            int headbase = ((n0 - 512) >> 5) & 7;
            int cl = tid >> 2;
            int dim = cl & 31;
            int hd  = headbase + (cl >> 5);
            size_t obase = (((size_t)b*8 + hd)*32 + dim) * 1024 + keybase;
            #pragma unroll
            for (int pz = 0; pz < 4; ++pz) {
                int ci  = (tid & 3) * 4 + pz;
                int ktl = ci >> 3, c = ci & 7;
                v8s val = *(const v8s*)&VT[cl*136 + ktl*64 + c*8];
                *(v8s*)&vt[obase + ktl*64 + ((c ^ (dim & 7)) << 3)] = val;
            }
        }
    }
}

// ---------------------------------------------------------------------------
// K2 attn: round-6 shape (4 waves, 64-row Q-tile, 1024 blocks, XCD-aligned
// bid%8==h) with the bias gather REVERTED to LDS (round-4 mechanism): 8 KB
// bf16 table staged per block via v8s copies; per-tile C-init = 16
// ds_read_u16 gathers via the register-pipelined packed u16 indices.
// LDS ~= 33 KB -> 4 blocks/CU (16 waves/CU).
// ---------------------------------------------------------------------------
__global__ __launch_bounds__(256)
void attn_mfma(const short* __restrict__ qh, const short* __restrict__ kh,
               const short* __restrict__ vt,
               const unsigned long long* __restrict__ bi,
               const unsigned short* __restrict__ tbl_bf,
               short* __restrict__ yh)
{
    __shared__ __align__(16) short Kh[2][2048];        // [64][32] fp16 per buf
    __shared__ __align__(16) short Vts[2][2048];       // [32][64] bf16 per buf
    __shared__ __align__(16) short Psb[4*16*68];       // per-wave P (bf16)
    __shared__ __align__(16) unsigned short tb16[4096];// bias table bf16

    int bh  = blockIdx.x & 63;   // bid%8 == h (XCD-aligned)
    int qt2 = blockIdx.x >> 6;   // 0..15
    int h   = bh & 7;
    int b   = bh >> 3;
    int tid = threadIdx.x;
    int w    = tid >> 6;        // 0..3
    int lane = tid & 63;
    int t    = lane & 15;
    int quad = lane >> 4;
    int lr8 = lane >> 3, lc8 = lane & 7;

    // stage bf16 bias table for this head (2 x v8s per thread, coalesced)
    {
        const v8s* src = (const v8s*)(tbl_bf + h*4096);
        v8s* dst = (v8s*)tb16;
        dst[tid]       = src[tid];
        dst[tid + 256] = src[tid + 256];
    }

    size_t qoff = ((size_t)bh*1024 + qt2*64 + w*16 + t) * 32 + quad*8;
    v8h qf = *(const v8h*)(qh + qoff);

    v4f Oacc[2] = {{0,0,0,0},{0,0,0,0}};
    float lsum[4] = {0,0,0,0};

    size_t kgbase = (size_t)bh * 32768;
    const unsigned long long* bmb = bi + (size_t)(qt2*4 + w)*4096 + lane;
    int qrow0 = qt2*64 + w*16 + quad*4;
    int swzS = (quad ^ ((t >> 1) & 3)) << 3;

    // stage tile 0 into buffer 0 (2 gld16 per wave: w<2 -> K, w>=2 -> V)
    if (w < 2) {
        gld16(kh + kgbase + (w*2+0)*512 + lane*8, &Kh[0][(w*2+0)*512]);
        gld16(kh + kgbase + (w*2+1)*512 + lane*8, &Kh[0][(w*2+1)*512]);
    } else {
        int v0 = w - 2;
        gld16(vt + kgbase + (size_t)(v0*16 + lr8)*1024 + lc8*8,     &Vts[0][(v0*2+0)*512]);
        gld16(vt + kgbase + (size_t)(v0*16 + 8 + lr8)*1024 + lc8*8, &Vts[0][(v0*2+1)*512]);
    }
    unsigned long long curb[4];
    #pragma unroll
    for (int g = 0; g < 4; ++g) curb[g] = bmb[g*64];

    #pragma unroll 1
    for (int kt = 0; kt < 16; ++kt) {
        int cur = kt & 1;
        __syncthreads();   // tile loads + tb16 staging landed; prior reads done
        unsigned long long nxtb[4];
        if (kt < 15) {
            int nkt = kt + 1, nb = cur ^ 1;
            if (w < 2) {
                gld16(kh + kgbase + (size_t)nkt*2048 + (w*2+0)*512 + lane*8,
                      &Kh[nb][(w*2+0)*512]);
                gld16(kh + kgbase + (size_t)nkt*2048 + (w*2+1)*512 + lane*8,
                      &Kh[nb][(w*2+1)*512]);
            } else {
                int v0 = w - 2;
                gld16(vt + kgbase + (size_t)(v0*16 + lr8)*1024 + nkt*64 + lc8*8,
                      &Vts[nb][(v0*2+0)*512]);
                gld16(vt + kgbase + (size_t)(v0*16 + 8 + lr8)*1024 + nkt*64 + lc8*8,
                      &Vts[nb][(v0*2+1)*512]);
            }
            #pragma unroll
            for (int g = 0; g < 4; ++g) nxtb[g] = bmb[nkt*256 + g*64];
        }

        // S = bias + Q K^T (fp16, 1 pass), exp2 domain; bias from LDS bf16
        v4f S[4];
        #pragma unroll
        for (int g = 0; g < 4; ++g) {
            unsigned long long cb = curb[g];
            v4f c;
            c[0] = ffrom((uint32_t)tb16[(uint32_t)cb & 0xFFFFu] << 16);
            c[1] = ffrom((uint32_t)tb16[(uint32_t)(cb >> 16) & 0xFFFFu] << 16);
            c[2] = ffrom((uint32_t)tb16[(uint32_t)(cb >> 32) & 0xFFFFu] << 16);
            c[3] = ffrom((uint32_t)tb16[(uint32_t)(cb >> 48)] << 16);
            v8h kb = *(const v8h*)&Kh[cur][(g*16 + t)*32 + swzS];
            S[g] = MFMAH(qf, kb, c);
        }

        // p = exp2(S); P cols are contiguous actual keys 4t+g -> packed b64
        #pragma unroll
        for (int r = 0; r < 4; ++r) {
            float p0 = EXP2(S[0][r]);
            float p1 = EXP2(S[1][r]);
            float p2 = EXP2(S[2][r]);
            float p3 = EXP2(S[3][r]);
            lsum[r] += (p0 + p1) + (p2 + p3);
            uint2 pk;
            pk.x = pack_bf_rh(p0, p1);
            pk.y = pack_bf_rh(p2, p3);
            *(uint2*)&Psb[(w*16 + quad*4 + r)*68 + t*4] = pk;
        }

        // O += P V (same-wave LDS dependency, no barrier)
        #pragma unroll
        for (int ks = 0; ks < 2; ++ks) {
            v8s pf = *(const v8s*)&Psb[(w*16 + t)*68 + ks*32 + quad*8];
            int vsw = ((ks*4 + quad) ^ (t & 7)) << 3;
            #pragma unroll
            for (int g = 0; g < 2; ++g) {
                v8s vf = *(const v8s*)&Vts[cur][(g*16 + t)*64 + vsw];
                Oacc[g] = MFMA(pf, vf, Oacc[g]);
            }
        }
        #pragma unroll
        for (int g = 0; g < 4; ++g) curb[g] = nxtb[g];
    }

    // epilogue: reduce l, normalize, write swizzled fp16 y
    #pragma unroll
    for (int r = 0; r < 4; ++r) {
        float l = lsum[r];
        l += __shfl_xor(l, 1); l += __shfl_xor(l, 2);
        l += __shfl_xor(l, 4); l += __shfl_xor(l, 8);
        float inv = 1.0f / l;
        int qrow = qrow0 + r;
        int m = b*1024 + qrow;
        size_t mbase = (size_t)m * 256;
        int mk = m & 7;
        #pragma unroll
        for (int g = 0; g < 2; ++g) {
            float o = Oacc[g][r] * inv;
            int c = h*4 + g*2 + (t >> 3);
            int chp = ((c ^ mk) << 3) | (t & 7);
            yh[mbase + chp] = f2h(o);
        }
    }
}

// ---------------------------------------------------------------------------
// K3 output projection: fp16 1-pass MFMA GEMM, TM=64 TN=64, BK=128.
// ---------------------------------------------------------------------------
__global__ __launch_bounds__(256)
void gemm_proj(const short* __restrict__ Ah_g, const short* __restrict__ Wh_g,
               const float* __restrict__ bias, float* __restrict__ C, int N)
{
    __shared__ __align__(16) short As[2][4096];   // [64][64] fp16 per buf
    __shared__ __align__(16) short Ws[2][4096];

    int tid  = threadIdx.x;
    int w    = tid >> 6;
    int lane = tid & 63;
    int t    = lane & 15;
    int quad = lane >> 4;
    int m0 = blockIdx.y * 64, n0 = blockIdx.x * 64;
    int Mw = (w >> 1) * 32, Nw = (w & 1) * 32;

    v4f acc[2][2];
    #pragma unroll
    for (int mt = 0; mt < 2; ++mt)
        #pragma unroll
        for (int nt = 0; nt < 2; ++nt) acc[mt][nt] = (v4f){0,0,0,0};

    int lr8 = lane >> 3, lc8 = lane & 7;
    #pragma unroll 1
    for (int kt2 = 0; kt2 < 2; ++kt2) {
        __syncthreads();
        #pragma unroll
        for (int half = 0; half < 2; ++half) {
            int kt = kt2*2 + half;
            #pragma unroll
            for (int i = 0; i < 2; ++i) {
                size_t grow = (size_t)(m0 + w*16 + i*8 + lr8) * 256 + kt*64 + lc8*8;
                gld16(Ah_g + grow, &As[half][(w*16 + i*8) * 64]);
            }
            #pragma unroll
            for (int i = 0; i < 2; ++i) {
                size_t grow = (size_t)(n0 + w*16 + i*8 + lr8) * 256 + kt*64 + lc8*8;
                gld16(Wh_g + grow, &Ws[half][(w*16 + i*8) * 64]);
            }
        }
        __syncthreads();
        #pragma unroll
        for (int half = 0; half < 2; ++half) {
            #pragma unroll
            for (int kk = 0; kk < 2; ++kk) {
                int cp = ((kk*4 + quad) ^ (t & 7)) << 3;
                v8h bh8[2];
                #pragma unroll
                for (int nt = 0; nt < 2; ++nt)
                    bh8[nt] = *(const v8h*)&Ws[half][(Nw + nt*16 + t)*64 + cp];
                #pragma unroll
                for (int mt = 0; mt < 2; ++mt) {
                    v8h ah = *(const v8h*)&As[half][(Mw + mt*16 + t)*64 + cp];
                    #pragma unroll
                    for (int nt = 0; nt < 2; ++nt)
                        acc[mt][nt] = MFMAH(ah, bh8[nt], acc[mt][nt]);
                }
            }
        }
    }

    #pragma unroll
    for (int nt = 0; nt < 2; ++nt) {
        float bv = bias[n0 + Nw + nt*16 + t];
        #pragma unroll
        for (int mt = 0; mt < 2; ++mt)
            #pragma unroll
            for (int r = 0; r < 4; ++r) acc[mt][nt][r] += bv;
    }
    #pragma unroll
    for (int mt = 0; mt < 2; ++mt)
        #pragma unroll
        for (int r = 0; r < 4; ++r) {
            int m = m0 + Mw + mt*16 + quad*4 + r;
            #pragma unroll
            for (int nt = 0; nt < 2; ++nt)
                C[(size_t)m * N + n0 + Nw + nt*16 + t] = acc[mt][nt][r];
        }
}

// ---------------------------------------------------------------------------
extern "C" void kernel_launch(void* const* d_in, const int* in_sizes, int n_in,
                              void* d_out, int out_size, void* d_ws, size_t ws_size,
                              hipStream_t stream)
{
    const float* x     = (const float*)d_in[0];
    const int*   rpi   = (const int*)d_in[3];
    const float* rct   = (const float*)d_in[4];
    const float* qkvw  = (const float*)d_in[5];
    const float* qkvb  = (const float*)d_in[6];
    const float* qe    = (const float*)d_in[7];
    const float* temp  = (const float*)d_in[8];
    const float* projw = (const float*)d_in[9];
    const float* projb = (const float*)d_in[10];
    const float* fc1w  = (const float*)d_in[11];
    const float* fc1b  = (const float*)d_in[12];
    const float* fc2w  = (const float*)d_in[13];
    const float* fc2b  = (const float*)d_in[14];

    char* p = (char*)d_ws;
    unsigned short* tbl_bf = (unsigned short*)p; p += 65536;  // [8][4096] bf16
    short* y     = (short*)p;  p += 4194304;   // attn output (fp16, swizzled)
    short* wph   = (short*)p;  p += 131072;
    short* qh    = (short*)p;  p += 4194304;
    short* kh    = (short*)p;  p += 4194304;
    short* vt    = (short*)p;  p += 4194304;
    unsigned long long* bi = (unsigned long long*)p; p += 2097152;
    float* out   = (float*)d_out;

    // 1) fused: qkv GEMM (fp32-staged) + CPB MLP (bf16 table) + wp convert
    //    + rpi pack
    fused_qkv<<<927, 256, 0, stream>>>(x, qkvw, projw, rct,
                                       fc1w, fc1b, fc2w, fc2b,
                                       qkvb, qe, temp, rpi,
                                       qh, kh, vt, tbl_bf, wph, bi);

    // 2) attention: 4-wave / 64-row Q-tiles / 1024 blocks, LDS bf16 bias
    attn_mfma<<<1024, 256, 0, stream>>>(qh, kh, vt, bi, tbl_bf, y);

    // 3) output projection -> d_out (fp32)
    dim3 g2(256/64, 8192/64);
    gemm_proj<<<g2, 256, 0, stream>>>(y, wph, projb, out, 256);
}